// Round 1
// baseline (126.262 us; speedup 1.0000x reference)
//
#include <hip/hip_runtime.h>

// Problem constants from setup_inputs(): feature_seq (B=2, C=64, N=512) fp32.
// Window lengths: [256, 1024, 512, 512]; output i has shape (B, N, C, L_i),
// concatenated flat in d_out.
constexpr int B = 2;
constexpr int C = 64;   // log2 = 6
constexpr int N = 512;  // log2 = 9

// Each thread writes one float4 along the innermost L axis.
// Flat float4 index t = ((b*N + n)*C + c)*(L/4) + l4.
template <int L>
__global__ __launch_bounds__(256)
void win_kernel(const float* __restrict__ in, float* __restrict__ out) {
    constexpr int HALF = L / 2;
    constexpr int L4 = L / 4;
    constexpr int L4_BITS = (L == 256) ? 6 : (L == 512) ? 7 : 8;

    int t = blockIdx.x * blockDim.x + threadIdx.x;

    int l4 = t & (L4 - 1);
    int rest = t >> L4_BITS;
    int c = rest & (C - 1);
    rest >>= 6;               // /C
    int n = rest & (N - 1);
    int b = rest >> 9;        // /N

    const float* __restrict__ row = in + (b * C + c) * N;
    int idx = n - HALF + (l4 << 2);

    float4 v;
    v.x = ((unsigned)(idx)     < (unsigned)N) ? row[idx]     : 0.0f;
    v.y = ((unsigned)(idx + 1) < (unsigned)N) ? row[idx + 1] : 0.0f;
    v.z = ((unsigned)(idx + 2) < (unsigned)N) ? row[idx + 2] : 0.0f;
    v.w = ((unsigned)(idx + 3) < (unsigned)N) ? row[idx + 3] : 0.0f;

    reinterpret_cast<float4*>(out)[t] = v;
}

extern "C" void kernel_launch(void* const* d_in, const int* in_sizes, int n_in,
                              void* d_out, int out_size, void* d_ws, size_t ws_size,
                              hipStream_t stream) {
    const float* in = (const float*)d_in[0];
    float* out = (float*)d_out;

    // Output float offsets in return order: L=256, L=1024, L=512, L=512.
    constexpr long long SZ256  = (long long)B * N * C * 256;   // 16,777,216
    constexpr long long SZ1024 = (long long)B * N * C * 1024;  // 67,108,864
    constexpr long long SZ512  = (long long)B * N * C * 512;   // 33,554,432

    float* out0 = out;                          // L=256
    float* out1 = out0 + SZ256;                 // L=1024
    float* out2 = out1 + SZ1024;                // L=512 (#1)
    float* out3 = out2 + SZ512;                 // L=512 (#2)

    constexpr int THREADS = 256;
    constexpr int G256  = (int)(SZ256  / 4 / THREADS);  // 16384 blocks
    constexpr int G1024 = (int)(SZ1024 / 4 / THREADS);  // 65536 blocks
    constexpr int G512  = (int)(SZ512  / 4 / THREADS);  // 32768 blocks

    win_kernel<256> <<<G256,  THREADS, 0, stream>>>(in, out0);
    win_kernel<1024><<<G1024, THREADS, 0, stream>>>(in, out1);
    win_kernel<512> <<<G512,  THREADS, 0, stream>>>(in, out2);
    win_kernel<512> <<<G512,  THREADS, 0, stream>>>(in, out3);
}

// Round 3
// 123.512 us; speedup vs baseline: 1.0223x; 1.0223x over previous
//
#include <hip/hip_runtime.h>

// feature_seq (B=2, C=64, N=512) fp32. Window lengths [256, 1024, 512, 512].
// Output i is (B, N, C, L_i), concatenated flat in d_out.
// out[b][n][c][l] = (0 <= n - L/2 + l < N) ? in[b][c][n - L/2 + l] : 0
//
// Single fused kernel: grid partitioned into 4 block-uniform segments (one per
// output). Each block writes 64 KB (256 threads x 4 x float4), every store
// instruction wave-contiguous. Non-temporal stores (native clang ext_vector
// type — HIP_vector_type float4 is rejected by the builtin).

constexpr int B = 2;
constexpr int C = 64;   // log2 = 6
constexpr int N = 512;  // log2 = 9

constexpr int SZ256  = B * N * C * 256;   // 16,777,216 floats
constexpr int SZ1024 = B * N * C * 1024;  // 67,108,864
constexpr int SZ512  = B * N * C * 512;   // 33,554,432

// float4 blocks (1024 float4 = 64 KB per block)
constexpr int BLK256  = SZ256  / 4 / 1024;  // 4096
constexpr int BLK1024 = SZ1024 / 4 / 1024;  // 16384
constexpr int BLK512  = SZ512  / 4 / 1024;  // 8192
constexpr int NBLK = BLK256 + BLK1024 + 2 * BLK512;  // 36864

typedef float f32x4 __attribute__((ext_vector_type(4)));

template <int L>
__device__ __forceinline__ void do_seg(const float* __restrict__ in,
                                       float* __restrict__ out,
                                       int blk, int tid) {
    constexpr int HALF = L / 2;
    constexpr int L4 = L / 4;
    constexpr int L4_BITS = (L == 256) ? 6 : (L == 512) ? 7 : 8;

    const int base = blk * 1024;
    f32x4* __restrict__ out4 = reinterpret_cast<f32x4*>(out);

#pragma unroll
    for (int k = 0; k < 4; ++k) {
        int t = base + k * 256 + tid;     // flat float4 index in this output

        int l4 = t & (L4 - 1);
        int rest = t >> L4_BITS;
        int c = rest & (C - 1);
        rest >>= 6;                        // / C
        int n = rest & (N - 1);
        int b = rest >> 9;                 // / N

        const float* __restrict__ row = in + (b * C + c) * N;
        int idx = n - HALF + (l4 << 2);

        f32x4 v;
        v.x = ((unsigned)(idx)     < (unsigned)N) ? row[idx]     : 0.0f;
        v.y = ((unsigned)(idx + 1) < (unsigned)N) ? row[idx + 1] : 0.0f;
        v.z = ((unsigned)(idx + 2) < (unsigned)N) ? row[idx + 2] : 0.0f;
        v.w = ((unsigned)(idx + 3) < (unsigned)N) ? row[idx + 3] : 0.0f;

        __builtin_nontemporal_store(v, out4 + t);
    }
}

__global__ __launch_bounds__(256)
void msw_fused_kernel(const float* __restrict__ in, float* __restrict__ out) {
    const int blk = blockIdx.x;
    const int tid = threadIdx.x;

    if (blk < BLK256) {
        do_seg<256>(in, out, blk, tid);
    } else if (blk < BLK256 + BLK1024) {
        do_seg<1024>(in, out + SZ256, blk - BLK256, tid);
    } else if (blk < BLK256 + BLK1024 + BLK512) {
        do_seg<512>(in, out + SZ256 + SZ1024, blk - (BLK256 + BLK1024), tid);
    } else {
        do_seg<512>(in, out + SZ256 + SZ1024 + SZ512,
                    blk - (BLK256 + BLK1024 + BLK512), tid);
    }
}

extern "C" void kernel_launch(void* const* d_in, const int* in_sizes, int n_in,
                              void* d_out, int out_size, void* d_ws, size_t ws_size,
                              hipStream_t stream) {
    const float* in = (const float*)d_in[0];
    float* out = (float*)d_out;

    msw_fused_kernel<<<NBLK, 256, 0, stream>>>(in, out);
}

// Round 4
// 118.373 us; speedup vs baseline: 1.0666x; 1.0434x over previous
//
#include <hip/hip_runtime.h>

// feature_seq (B=2, C=64, N=512) fp32. Window lengths [256, 1024, 512, 512].
// Output i is (B, N, C, L_i), concatenated flat in d_out.
// out[b][n][c][l] = (0 <= n - L/2 + l < N) ? in[b][c][n - L/2 + l] : 0
//
// One fused kernel, 64 KB per block (256 thr x 4 x float4), nt stores.
// Interior float4s: ONE (possibly 4B-aligned-only) vector load instead of 4
// scalar loads — cuts VMEM instruction/TA pressure ~2.5x. Fully-out-of-range
// float4s (50% of the L=1024 tensor!) load nothing. Partial overlap (<=2
// float4 per row-window) takes the scalar path under exec mask.

constexpr int B = 2;
constexpr int C = 64;   // log2 = 6
constexpr int N = 512;  // log2 = 9

constexpr int SZ256  = B * N * C * 256;   // 16,777,216 floats
constexpr int SZ1024 = B * N * C * 1024;  // 67,108,864
constexpr int SZ512  = B * N * C * 512;   // 33,554,432

constexpr int BLK256  = SZ256  / 4 / 1024;  // 4096 blocks
constexpr int BLK1024 = SZ1024 / 4 / 1024;  // 16384
constexpr int BLK512  = SZ512  / 4 / 1024;  // 8192
constexpr int NBLK = BLK256 + BLK1024 + 2 * BLK512;  // 36864

typedef float f32x4 __attribute__((ext_vector_type(4)));
typedef float f32x4u __attribute__((ext_vector_type(4), aligned(4)));

template <int L>
__device__ __forceinline__ void do_seg(const float* __restrict__ in,
                                       float* __restrict__ out,
                                       int blk, int tid) {
    constexpr int HALF = L / 2;
    constexpr int L4 = L / 4;
    constexpr int L4_BITS = (L == 256) ? 6 : (L == 512) ? 7 : 8;

    const int base = blk * 1024;
    f32x4* __restrict__ out4 = reinterpret_cast<f32x4*>(out);

#pragma unroll
    for (int k = 0; k < 4; ++k) {
        int t = base + k * 256 + tid;     // flat float4 index in this output

        int l4 = t & (L4 - 1);
        int rest = t >> L4_BITS;
        int c = rest & (C - 1);
        rest >>= 6;                        // / C
        int n = rest & (N - 1);
        int b = rest >> 9;                 // / N

        const float* __restrict__ row = in + (b * C + c) * N;
        int idx = n - HALF + (l4 << 2);

        f32x4 v;
        if ((unsigned)idx < (unsigned)(N - 3)) {
            // fully in range: single vector load (dword-aligned ok on gfx950)
            v = *reinterpret_cast<const f32x4u*>(row + idx);
        } else if (idx >= N || idx <= -4) {
            // fully out of range: structural zero, no load
            v.x = v.y = v.z = v.w = 0.0f;
        } else {
            // partial overlap (rare, <=2 float4 per row-window)
            v.x = ((unsigned)(idx)     < (unsigned)N) ? row[idx]     : 0.0f;
            v.y = ((unsigned)(idx + 1) < (unsigned)N) ? row[idx + 1] : 0.0f;
            v.z = ((unsigned)(idx + 2) < (unsigned)N) ? row[idx + 2] : 0.0f;
            v.w = ((unsigned)(idx + 3) < (unsigned)N) ? row[idx + 3] : 0.0f;
        }

        __builtin_nontemporal_store(v, out4 + t);
    }
}

__global__ __launch_bounds__(256)
void msw_fused_kernel(const float* __restrict__ in, float* __restrict__ out) {
    const int blk = blockIdx.x;
    const int tid = threadIdx.x;

    if (blk < BLK256) {
        do_seg<256>(in, out, blk, tid);
    } else if (blk < BLK256 + BLK1024) {
        do_seg<1024>(in, out + SZ256, blk - BLK256, tid);
    } else if (blk < BLK256 + BLK1024 + BLK512) {
        do_seg<512>(in, out + SZ256 + SZ1024, blk - (BLK256 + BLK1024), tid);
    } else {
        do_seg<512>(in, out + SZ256 + SZ1024 + SZ512,
                    blk - (BLK256 + BLK1024 + BLK512), tid);
    }
}

extern "C" void kernel_launch(void* const* d_in, const int* in_sizes, int n_in,
                              void* d_out, int out_size, void* d_ws, size_t ws_size,
                              hipStream_t stream) {
    const float* in = (const float*)d_in[0];
    float* out = (float*)d_out;

    msw_fused_kernel<<<NBLK, 256, 0, stream>>>(in, out);
}